// Round 1
// 2724.104 us; speedup vs baseline: 5.1387x; 5.1387x over previous
//
#include <hip/hip_runtime.h>
#include <hip/hip_bf16.h>

#define L_ 6
#define D_ 768
#define H_ 12
#define HD_ 64
#define FF_ 3072
#define V_ 32000
#define B_ 4
#define T_ 1024
#define M_ 4096  // B_*T_

typedef __attribute__((ext_vector_type(8))) short short8;   // 8 bf16 = 4 VGPRs (MFMA A/B frag)
typedef __attribute__((ext_vector_type(4))) float f32x4;    // MFMA C/D frag
typedef __hip_bfloat16 bf16;

__device__ __forceinline__ unsigned short f2bu(float f) {
    bf16 b = __float2bfloat16(f);
    return *reinterpret_cast<unsigned short*>(&b);
}

// ---------------- embedding: h[b,t,:] = tok_emb[x[b,t],:] + pos_emb[t,:] ----------------
__global__ void embed_kernel(const int* __restrict__ x, const float* __restrict__ tok,
                             const float* __restrict__ pos, float* __restrict__ h) {
    int rt = blockIdx.x;            // b*T + t
    int t = rt & (T_ - 1);
    int tokid = x[rt];
    const float* ts = tok + (size_t)tokid * D_;
    const float* ps = pos + (size_t)t * D_;
    float* hr = h + (size_t)rt * D_;
    for (int k = threadIdx.x; k < D_; k += 256)
        hr[k] = ts[k] + ps[k];
}

// ---------------- layernorm (fp32 in, bf16 out), one 256-thread block per row ----------------
__global__ void ln_kernel(const float* __restrict__ x, const float* __restrict__ sc,
                          const float* __restrict__ bi, bf16* __restrict__ out) {
    int row = blockIdx.x, tid = threadIdx.x;
    const float* xr = x + (size_t)row * D_;
    float v0 = xr[tid], v1 = xr[tid + 256], v2 = xr[tid + 512];
    float s = v0 + v1 + v2;
#pragma unroll
    for (int m = 32; m; m >>= 1) s += __shfl_xor(s, m);
    __shared__ float r1[4], r2[4];
    if ((tid & 63) == 0) r1[tid >> 6] = s;
    __syncthreads();
    float mean = (r1[0] + r1[1] + r1[2] + r1[3]) * (1.f / D_);
    float d0 = v0 - mean, d1 = v1 - mean, d2 = v2 - mean;
    float q = d0 * d0 + d1 * d1 + d2 * d2;
#pragma unroll
    for (int m = 32; m; m >>= 1) q += __shfl_xor(q, m);
    if ((tid & 63) == 0) r2[tid >> 6] = q;
    __syncthreads();
    float var = (r2[0] + r2[1] + r2[2] + r2[3]) * (1.f / D_);
    float rs = rsqrtf(var + 1e-5f);
    bf16* orow = out + (size_t)row * D_;
    orow[tid]       = __float2bfloat16(d0 * rs * sc[tid]       + bi[tid]);
    orow[tid + 256] = __float2bfloat16(d1 * rs * sc[tid + 256] + bi[tid + 256]);
    orow[tid + 512] = __float2bfloat16(d2 * rs * sc[tid + 512] + bi[tid + 512]);
}

// ---------------- transpose + fp32->bf16: out[n+off][k] = in[k][n], layer-batched in z ----------------
__global__ void transpose_cvt(const float* __restrict__ in, bf16* __restrict__ out,
                              int K, int N, size_t inLS, size_t outLS,
                              int outStride, int outRowOff) {
    in  += (size_t)blockIdx.z * inLS;
    out += (size_t)blockIdx.z * outLS;
    __shared__ float tile[32][33];
    int n0 = blockIdx.x * 32, k0 = blockIdx.y * 32;
    int tx = threadIdx.x, ty = threadIdx.y;  // 32 x 8
#pragma unroll
    for (int i = 0; i < 4; i++)
        tile[ty + i * 8][tx] = in[(size_t)(k0 + ty + i * 8) * N + n0 + tx];
    __syncthreads();
#pragma unroll
    for (int i = 0; i < 4; i++)
        out[(size_t)(n0 + ty + i * 8 + outRowOff) * outStride + k0 + tx] =
            __float2bfloat16(tile[tx][ty + i * 8]);
}

// ---------------- repack qkv fp32 [M][2304] -> bf16 Qb/Kb [BH][T][64] (Q pre-scaled 1/8), Vt [BH][64][T] ----
__global__ __launch_bounds__(256) void repack_qkv(const float* __restrict__ qkv,
                                                  bf16* __restrict__ Qb, bf16* __restrict__ Kb,
                                                  bf16* __restrict__ Vt) {
    int bh = blockIdx.y;             // b*H + h
    int b = bh / H_, h = bh % H_;
    int t0 = blockIdx.x * 64;
    int tid = threadIdx.x;
    __shared__ float vt[64][65];
    const float* base = qkv + (size_t)(b * T_ + t0) * (3 * D_) + h * HD_;
#pragma unroll
    for (int p = 0; p < 4; p++) {
        int idx = tid + p * 256;
        int r = idx >> 4;            // t row 0..63
        int d = (idx & 15) * 4;      // d 0..60
        const float* rp = base + (size_t)r * (3 * D_);
        float4 qv = *(const float4*)(rp + d);
        float4 kv = *(const float4*)(rp + D_ + d);
        float4 vv = *(const float4*)(rp + 2 * D_ + d);
        ushort4 qo, ko;
        qo.x = f2bu(qv.x * 0.125f); qo.y = f2bu(qv.y * 0.125f);
        qo.z = f2bu(qv.z * 0.125f); qo.w = f2bu(qv.w * 0.125f);
        ko.x = f2bu(kv.x); ko.y = f2bu(kv.y); ko.z = f2bu(kv.z); ko.w = f2bu(kv.w);
        *(ushort4*)(Qb + ((size_t)bh * T_ + t0 + r) * HD_ + d) = qo;
        *(ushort4*)(Kb + ((size_t)bh * T_ + t0 + r) * HD_ + d) = ko;
        vt[r][d + 0] = vv.x; vt[r][d + 1] = vv.y; vt[r][d + 2] = vv.z; vt[r][d + 3] = vv.w;
    }
    __syncthreads();
#pragma unroll
    for (int p = 0; p < 4; p++) {
        int idx = tid + p * 256;
        int d = idx >> 4;            // 0..63
        int t4 = (idx & 15) * 4;     // 0..60
        ushort4 vo;
        vo.x = f2bu(vt[t4 + 0][d]); vo.y = f2bu(vt[t4 + 1][d]);
        vo.z = f2bu(vt[t4 + 2][d]); vo.w = f2bu(vt[t4 + 3][d]);
        *(ushort4*)(Vt + ((size_t)bh * HD_ + d) * T_ + t0 + t4) = vo;
    }
}

// ---------------- MFMA flash attention ----------------
// One wave per (b,h,16-query tile). 32-key tiles. Swapped QK^T (A=K, B=Q) so each lane
// holds 8 scores of ONE query row (q = lane&15): online softmax = in-lane + shfl_xor(16,32).
// Fragment layouts are the gemm_bt-verified ones:
//   A-frag: A[lane&15][(lane>>4)*8 + j]   B-frag: Bt[lane&15][(lane>>4)*8 + j]
//   D: row m = (lane>>4)*4 + reg, col n = lane&15
__global__ __launch_bounds__(256) void fattn(const bf16* __restrict__ Qb, const bf16* __restrict__ Kb,
                                             const bf16* __restrict__ Vt, bf16* __restrict__ o) {
    int nwg = (int)gridDim.x;                          // 768 (multiple of 8)
    int wg = (int)blockIdx.x;
    wg = (wg & 7) * (nwg >> 3) + (wg >> 3);            // XCD-contiguous swizzle (bijective: 768%8==0)
    int wid = wg * 4 + (threadIdx.x >> 6);
    int lane = threadIdx.x & 63;
    int qt = wid & 63;                                 // 64 q-tiles per (b,h)
    int bh = wid >> 6;
    int q0 = qt * 16;
    int q15 = lane & 15, g = lane >> 4;
    int qg = q0 + q15;

    const bf16* Qp = Qb + ((size_t)bh * T_ + q0 + q15) * HD_ + g * 8;
    short8 qf0 = *(const short8*)Qp;                   // d in [0,32)
    short8 qf1 = *(const short8*)(Qp + 32);            // d in [32,64)
    const bf16* Kbh = Kb + (size_t)bh * T_ * HD_;
    const bf16* Vbh = Vt + (size_t)bh * HD_ * T_;

    f32x4 o0 = {0.f, 0.f, 0.f, 0.f}, o1 = o0, o2 = o0, o3 = o0;  // O[q=4g+r][d=i*16+q15]
    float m = -3.0e38f, lsum = 0.f;
    int nkt = (q0 + 15) / 32 + 1;

    for (int kt = 0; kt < nkt; kt++) {
        int k0 = kt * 32;
        const bf16* kp = Kbh + (size_t)(k0 + q15) * HD_ + g * 8;
        short8 kf00 = *(const short8*)(kp);                    // k-sub0, d-chunk0
        short8 kf01 = *(const short8*)(kp + 32);               // k-sub0, d-chunk1
        short8 kf10 = *(const short8*)(kp + 16 * HD_);         // k-sub1, d-chunk0
        short8 kf11 = *(const short8*)(kp + 16 * HD_ + 32);    // k-sub1, d-chunk1
        f32x4 s0 = {0.f, 0.f, 0.f, 0.f}, s1 = s0;
        // S^T[k][q]: lane holds q=q15, k = k0 + 4g + r (s0) / k0+16+4g+r (s1)
        s0 = __builtin_amdgcn_mfma_f32_16x16x32_bf16(kf00, qf0, s0, 0, 0, 0);
        s0 = __builtin_amdgcn_mfma_f32_16x16x32_bf16(kf01, qf1, s0, 0, 0, 0);
        s1 = __builtin_amdgcn_mfma_f32_16x16x32_bf16(kf10, qf0, s1, 0, 0, 0);
        s1 = __builtin_amdgcn_mfma_f32_16x16x32_bf16(kf11, qf1, s1, 0, 0, 0);

        if (kt == nkt - 1) {                                   // only the diagonal tile needs masking
            int kb = k0 + 4 * g;
#pragma unroll
            for (int r = 0; r < 4; r++) {
                if (kb + r > qg)      s0[r] = -3.0e38f;
                if (kb + 16 + r > qg) s1[r] = -3.0e38f;
            }
        }
        // online softmax for q = q15 (reduce 8 in-lane + across 4 lane-groups)
        float mx = fmaxf(fmaxf(fmaxf(s0[0], s0[1]), fmaxf(s0[2], s0[3])),
                         fmaxf(fmaxf(s1[0], s1[1]), fmaxf(s1[2], s1[3])));
        mx = fmaxf(mx, __shfl_xor(mx, 16));
        mx = fmaxf(mx, __shfl_xor(mx, 32));
        float mn = fmaxf(m, mx);
        float alpha = __expf(m - mn);
        m = mn;
        float p0[4], p1[4];
        float ls = 0.f;
#pragma unroll
        for (int r = 0; r < 4; r++) {
            p0[r] = __expf(s0[r] - mn);
            p1[r] = __expf(s1[r] - mn);
            ls += p0[r] + p1[r];
        }
        ls += __shfl_xor(ls, 16);
        ls += __shfl_xor(ls, 32);
        lsum = lsum * alpha + ls;

        // redistribute P to A-frag layout: pa[j] = P[q15][kk=8g+j]
        //   src lane group = 2*(g&1) + (j>>2), reg = j&3, sub = g>>1
        short8 pa;
#pragma unroll
        for (int j = 0; j < 8; j++) {
            int src = ((2 * (g & 1) + (j >> 2)) << 4) | q15;
            float v0 = __shfl(p0[j & 3], src);
            float v1 = __shfl(p1[j & 3], src);
            pa[j] = (short)f2bu((g >> 1) ? v1 : v0);
        }
        // alpha for this lane's O rows (q = 4g + r): fetch from lane 4g+r (its q15 == 4g+r)
        float al0 = __shfl(alpha, 4 * g + 0);
        float al1 = __shfl(alpha, 4 * g + 1);
        float al2 = __shfl(alpha, 4 * g + 2);
        float al3 = __shfl(alpha, 4 * g + 3);
        o0[0] *= al0; o0[1] *= al1; o0[2] *= al2; o0[3] *= al3;
        o1[0] *= al0; o1[1] *= al1; o1[2] *= al2; o1[3] *= al3;
        o2[0] *= al0; o2[1] *= al1; o2[2] *= al2; o2[3] *= al3;
        o3[0] *= al0; o3[1] *= al1; o3[2] *= al2; o3[3] *= al3;

        // PV: O[q][d] += P[q][k] * Vt[d][k]  (B-frag reads Vt rows, contiguous k)
        const bf16* vp = Vbh + (size_t)q15 * T_ + k0 + g * 8;
        short8 vf0 = *(const short8*)(vp);
        short8 vf1 = *(const short8*)(vp + 16 * T_);
        short8 vf2 = *(const short8*)(vp + 32 * T_);
        short8 vf3 = *(const short8*)(vp + 48 * T_);
        o0 = __builtin_amdgcn_mfma_f32_16x16x32_bf16(pa, vf0, o0, 0, 0, 0);
        o1 = __builtin_amdgcn_mfma_f32_16x16x32_bf16(pa, vf1, o1, 0, 0, 0);
        o2 = __builtin_amdgcn_mfma_f32_16x16x32_bf16(pa, vf2, o2, 0, 0, 0);
        o3 = __builtin_amdgcn_mfma_f32_16x16x32_bf16(pa, vf3, o3, 0, 0, 0);
    }

    float rl = 1.f / lsum;
    float rl0 = __shfl(rl, 4 * g + 0);
    float rl1 = __shfl(rl, 4 * g + 1);
    float rl2 = __shfl(rl, 4 * g + 2);
    float rl3 = __shfl(rl, 4 * g + 3);
    int b = bh / H_, h = bh % H_;
    bf16* ob = o + ((size_t)(b * T_ + q0 + 4 * g)) * D_ + h * HD_ + q15;
    {
        bf16* r0p = ob;
        r0p[0] = __float2bfloat16(o0[0] * rl0); r0p[16] = __float2bfloat16(o1[0] * rl0);
        r0p[32] = __float2bfloat16(o2[0] * rl0); r0p[48] = __float2bfloat16(o3[0] * rl0);
        bf16* r1p = ob + D_;
        r1p[0] = __float2bfloat16(o0[1] * rl1); r1p[16] = __float2bfloat16(o1[1] * rl1);
        r1p[32] = __float2bfloat16(o2[1] * rl1); r1p[48] = __float2bfloat16(o3[1] * rl1);
        bf16* r2p = ob + 2 * D_;
        r2p[0] = __float2bfloat16(o0[2] * rl2); r2p[16] = __float2bfloat16(o1[2] * rl2);
        r2p[32] = __float2bfloat16(o2[2] * rl2); r2p[48] = __float2bfloat16(o3[2] * rl2);
        bf16* r3p = ob + 3 * D_;
        r3p[0] = __float2bfloat16(o0[3] * rl3); r3p[16] = __float2bfloat16(o1[3] * rl3);
        r3p[32] = __float2bfloat16(o2[3] * rl3); r3p[48] = __float2bfloat16(o3[3] * rl3);
    }
}

// ---------------- bf16 MFMA GEMM, C = A[M,K] @ B[K,N] with B given transposed (Bt[N][K]) ----------------
// 128x128 tile, BK=32, 4 waves, each wave 64x64 via 4x4 grid of 16x16x32 MFMA.
template <bool OUT_BF16, bool RELU, bool HAS_BIAS, bool HAS_RES>
__global__ __launch_bounds__(256) void gemm_bt(const bf16* __restrict__ A, const bf16* __restrict__ Bt,
                                               const float* __restrict__ bias, const float* __restrict__ res,
                                               void* __restrict__ outp, int M, int N, int K) {
    __shared__ bf16 As[128 * 32];
    __shared__ bf16 Bs[128 * 32];
    int bn0 = blockIdx.x * 128, bm0 = blockIdx.y * 128;
    int tid = threadIdx.x;
    int lane = tid & 63, w = tid >> 6;
    int wm = (w & 1) * 64, wn = (w >> 1) * 64;
    f32x4 acc[4][4];
#pragma unroll
    for (int i = 0; i < 4; i++)
#pragma unroll
        for (int j = 0; j < 4; j++) acc[i][j] = (f32x4){0.f, 0.f, 0.f, 0.f};

    for (int kt = 0; kt < K; kt += 32) {
        __syncthreads();  // previous iteration's frag reads done before overwrite
#pragma unroll
        for (int p = 0; p < 2; p++) {
            int idx = tid + p * 256;
            int r = idx >> 2, c = idx & 3;  // row 0..127, 16B chunk 0..3
            *(uint4*)&As[r * 32 + c * 8] = *(const uint4*)(A + (size_t)(bm0 + r) * K + kt + c * 8);
            *(uint4*)&Bs[r * 32 + c * 8] = *(const uint4*)(Bt + (size_t)(bn0 + r) * K + kt + c * 8);
        }
        __syncthreads();
        short8 af[4], bfr[4];
#pragma unroll
        for (int i = 0; i < 4; i++)
            af[i] = *(const short8*)&As[(wm + i * 16 + (lane & 15)) * 32 + (lane >> 4) * 8];
#pragma unroll
        for (int j = 0; j < 4; j++)
            bfr[j] = *(const short8*)&Bs[(wn + j * 16 + (lane & 15)) * 32 + (lane >> 4) * 8];
#pragma unroll
        for (int i = 0; i < 4; i++)
#pragma unroll
            for (int j = 0; j < 4; j++)
                acc[i][j] = __builtin_amdgcn_mfma_f32_16x16x32_bf16(af[i], bfr[j], acc[i][j], 0, 0, 0);
    }

    // epilogue: D[row][col], col = lane&15, row = (lane>>4)*4 + reg   [m89/m91-verified]
    int r4 = (lane >> 4) * 4, cl = lane & 15;
#pragma unroll
    for (int i = 0; i < 4; i++) {
        int row0 = bm0 + wm + i * 16 + r4;
#pragma unroll
        for (int j = 0; j < 4; j++) {
            int col = bn0 + wn + j * 16 + cl;
            float bv = HAS_BIAS ? bias[col] : 0.f;
#pragma unroll
            for (int r = 0; r < 4; r++) {
                int row = row0 + r;
                float v = acc[i][j][r] + bv;
                if (HAS_RES) v += res[(size_t)row * N + col];
                if (RELU) v = fmaxf(v, 0.f);
                if (OUT_BF16)
                    ((bf16*)outp)[(size_t)row * N + col] = __float2bfloat16(v);
                else
                    ((float*)outp)[(size_t)row * N + col] = v;
            }
        }
    }
}

extern "C" void kernel_launch(void* const* d_in, const int* in_sizes, int n_in,
                              void* d_out, int out_size, void* d_ws, size_t ws_size,
                              hipStream_t stream) {
    const int*   x     = (const int*)d_in[0];
    const float* tok   = (const float*)d_in[1];
    const float* pos   = (const float*)d_in[2];
    const float* wq    = (const float*)d_in[3];
    const float* wk    = (const float*)d_in[4];
    const float* wv    = (const float*)d_in[5];
    const float* wo    = (const float*)d_in[6];
    const float* bo    = (const float*)d_in[7];
    const float* ln1s  = (const float*)d_in[8];
    const float* ln1b  = (const float*)d_in[9];
    const float* ln2s  = (const float*)d_in[10];
    const float* ln2b  = (const float*)d_in[11];
    const float* w1    = (const float*)d_in[12];
    const float* b1    = (const float*)d_in[13];
    const float* w2    = (const float*)d_in[14];
    const float* b2    = (const float*)d_in[15];
    const float* lnfs  = (const float*)d_in[16];
    const float* lnfb  = (const float*)d_in[17];
    const float* whead = (const float*)d_in[18];
    const float* bhead = (const float*)d_in[19];
    float* out = (float*)d_out;

    char* ws = (char*)d_ws;
    size_t off = 0;
    auto alloc = [&](size_t bytes) {
        void* p = ws + off;
        off += (bytes + 255) & ~(size_t)255;
        return p;
    };
    bf16*  Wqkv  = (bf16*)alloc((size_t)L_ * 3 * D_ * D_ * 2);   // [L][2304][768] bf16 (B^T, q|k|v packed)
    bf16*  Wot   = (bf16*)alloc((size_t)L_ * D_ * D_ * 2);       // [L][768][768]
    bf16*  W1t   = (bf16*)alloc((size_t)L_ * FF_ * D_ * 2);      // [L][3072][768]
    bf16*  W2t   = (bf16*)alloc((size_t)L_ * D_ * FF_ * 2);      // [L][768][3072]
    bf16*  Wht   = (bf16*)alloc((size_t)V_ * D_ * 2);            // [32000][768]
    float* h     = (float*)alloc((size_t)M_ * D_ * 4);           // residual stream, fp32
    bf16*  abuf  = (bf16*)alloc((size_t)M_ * D_ * 2);            // LN output
    float* qkv   = (float*)alloc((size_t)M_ * 3 * D_ * 4);       // q|k|v fp32
    bf16*  attno = (bf16*)alloc((size_t)M_ * D_ * 2);            // attention out
    bf16*  ffmid = (bf16*)alloc((size_t)M_ * FF_ * 2);           // relu(f@w1+b1)
    bf16*  Qb    = (bf16*)alloc((size_t)B_ * H_ * T_ * HD_ * 2); // [BH][T][64], pre-scaled by 1/8
    bf16*  Kb    = (bf16*)alloc((size_t)B_ * H_ * T_ * HD_ * 2); // [BH][T][64]
    bf16*  Vt    = (bf16*)alloc((size_t)B_ * H_ * T_ * HD_ * 2); // [BH][64][T]  (V transposed)
    (void)ws_size; (void)in_sizes; (void)n_in; (void)out_size;

    dim3 tb(32, 8);
    // weight convert+transpose (every call; ws is re-poisoned)
    transpose_cvt<<<dim3(D_ / 32, D_ / 32, L_), tb, 0, stream>>>(wq, Wqkv, D_, D_, (size_t)D_ * D_, (size_t)3 * D_ * D_, D_, 0);
    transpose_cvt<<<dim3(D_ / 32, D_ / 32, L_), tb, 0, stream>>>(wk, Wqkv, D_, D_, (size_t)D_ * D_, (size_t)3 * D_ * D_, D_, D_);
    transpose_cvt<<<dim3(D_ / 32, D_ / 32, L_), tb, 0, stream>>>(wv, Wqkv, D_, D_, (size_t)D_ * D_, (size_t)3 * D_ * D_, D_, 2 * D_);
    transpose_cvt<<<dim3(D_ / 32, D_ / 32, L_), tb, 0, stream>>>(wo, Wot, D_, D_, (size_t)D_ * D_, (size_t)D_ * D_, D_, 0);
    transpose_cvt<<<dim3(FF_ / 32, D_ / 32, L_), tb, 0, stream>>>(w1, W1t, D_, FF_, (size_t)D_ * FF_, (size_t)FF_ * D_, D_, 0);
    transpose_cvt<<<dim3(D_ / 32, FF_ / 32, L_), tb, 0, stream>>>(w2, W2t, FF_, D_, (size_t)FF_ * D_, (size_t)D_ * FF_, FF_, 0);
    transpose_cvt<<<dim3(V_ / 32, D_ / 32, 1), tb, 0, stream>>>(whead, Wht, D_, V_, 0, 0, D_, 0);

    embed_kernel<<<M_, 256, 0, stream>>>(x, tok, pos, h);

    for (int l = 0; l < L_; l++) {
        ln_kernel<<<M_, 256, 0, stream>>>(h, ln1s + l * D_, ln1b + l * D_, abuf);
        gemm_bt<false, false, false, false><<<dim3(3 * D_ / 128, M_ / 128), 256, 0, stream>>>(
            abuf, Wqkv + (size_t)l * 3 * D_ * D_, nullptr, nullptr, qkv, M_, 3 * D_, D_);
        repack_qkv<<<dim3(T_ / 64, B_ * H_), 256, 0, stream>>>(qkv, Qb, Kb, Vt);
        fattn<<<(B_ * H_ * 64) / 4, 256, 0, stream>>>(Qb, Kb, Vt, attno);
        gemm_bt<false, false, true, true><<<dim3(D_ / 128, M_ / 128), 256, 0, stream>>>(
            attno, Wot + (size_t)l * D_ * D_, bo + l * D_, h, h, M_, D_, D_);
        ln_kernel<<<M_, 256, 0, stream>>>(h, ln2s + l * D_, ln2b + l * D_, abuf);
        gemm_bt<true, true, true, false><<<dim3(FF_ / 128, M_ / 128), 256, 0, stream>>>(
            abuf, W1t + (size_t)l * FF_ * D_, b1 + l * FF_, nullptr, ffmid, M_, FF_, D_);
        gemm_bt<false, false, true, true><<<dim3(D_ / 128, M_ / 128), 256, 0, stream>>>(
            ffmid, W2t + (size_t)l * D_ * FF_, b2 + l * D_, h, h, M_, D_, FF_);
    }
    ln_kernel<<<M_, 256, 0, stream>>>(h, lnfs, lnfb, abuf);
    gemm_bt<false, false, true, false><<<dim3(V_ / 128, M_ / 128), 256, 0, stream>>>(
        abuf, Wht, bhead, nullptr, out, M_, V_, D_);
}